// Round 14
// baseline (938.234 us; speedup 1.0000x reference)
//
#include <hip/hip_runtime.h>
#include <hip/hip_fp16.h>

static constexpr int F = 64;       // IN_FEATS == HIDDEN
static constexpr int C = 16;       // NUM_CLASSES
static constexpr int EPB = 2048;   // edges per block (hist/partition)
static constexpr int BSH = 7;      // bucket shift: 128 nodes/bucket
static constexpr int NPB = 128;    // nodes per bucket
static constexpr int NBK = 782;    // ceil(100000/128)
static constexpr int SRCB = 17;    // src id bits (nNodes <= 131072)

// -------- prep: fp32->fp16 convert + per-block histogram + slice reservation
__global__ void prep(const float* __restrict__ x, __half* __restrict__ xh, int n4,
                     const int* __restrict__ dst, int* __restrict__ bucketCount,
                     int* __restrict__ blockHist, int nEdges) {
    int stride = gridDim.x * blockDim.x;
    for (int i = blockIdx.x * blockDim.x + threadIdx.x; i < n4; i += stride) {
        float4 v = ((const float4*)x)[i];
        __half2 p0 = __floats2half2_rn(v.x, v.y);
        __half2 p1 = __floats2half2_rn(v.z, v.w);
        uint2 o;
        o.x = *reinterpret_cast<unsigned*>(&p0);
        o.y = *reinterpret_cast<unsigned*>(&p1);
        ((uint2*)xh)[i] = o;
    }
    __shared__ int h[NBK];
    int t = threadIdx.x;
    for (int j = t; j < NBK; j += 256) h[j] = 0;
    __syncthreads();
    int e0 = blockIdx.x * EPB;
    for (int i = 0; i < EPB / 256; ++i) {
        int e = e0 + i * 256 + t;
        if (e < nEdges) atomicAdd(&h[dst[e] >> BSH], 1);
    }
    __syncthreads();
    for (int j = t; j < NBK; j += 256)
        blockHist[blockIdx.x * NBK + j] = h[j] ? atomicAdd(&bucketCount[j], h[j]) : 0;
}

// ------------- exclusive scan of NBK bucket counts (1 block, proven pattern)
__global__ void bucket_scan(const int* __restrict__ bucketCount,
                            int* __restrict__ bucketStart) {
    __shared__ int s[1024];
    int t = threadIdx.x;
    s[t] = (t < NBK) ? bucketCount[t] : 0;
    __syncthreads();
    for (int o = 1; o < 1024; o <<= 1) {
        int v = (t >= o) ? s[t - o] : 0;
        __syncthreads();
        s[t] += v;
        __syncthreads();
    }
    if (t < NBK) {
        bucketStart[t] = (t > 0) ? s[t - 1] : 0;
        if (t == NBK - 1) bucketStart[NBK] = s[t];
    }
}

// ------------- partition: place edges into pre-reserved bucket slices
__global__ void partition(const int* __restrict__ src, const int* __restrict__ dst,
                          const int* __restrict__ blockHist,
                          const int* __restrict__ bucketStart,
                          unsigned* __restrict__ pairs, int nEdges) {
    __shared__ int base[NBK];
    __shared__ int rank[NBK];
    int t = threadIdx.x;
    for (int j = t; j < NBK; j += 256) {
        rank[j] = 0;
        base[j] = bucketStart[j] + blockHist[blockIdx.x * NBK + j];
    }
    __syncthreads();
    int e0 = blockIdx.x * EPB;
    for (int i = 0; i < EPB / 256; ++i) {
        int e = e0 + i * 256 + t;
        if (e < nEdges) {
            int d = dst[e];
            int b = d >> BSH;
            int r = atomicAdd(&rank[b], 1);
            pairs[base[b] + r] =
                ((unsigned)(d & (NPB - 1)) << SRCB) | (unsigned)src[e];
        }
    }
}

// ---- agg_bucket: one block per bucket; unordered pairs -> LDS accumulate.
// 16-lane group per edge; lane q adds its 4 floats into accL[dloc][q*4..].
__global__ void agg_bucket(const __half* __restrict__ xh,
                           const unsigned* __restrict__ pairs,
                           const int* __restrict__ bucketStart,
                           float* __restrict__ agg, float* __restrict__ invdeg,
                           int nNodes) {
    __shared__ float accL[NPB * F];   // 32 KB
    __shared__ int cntL[NPB];
    int t = threadIdx.x;              // 512
    for (int i = t; i < NPB * F; i += 512) accL[i] = 0.0f;
    if (t < NPB) cntL[t] = 0;
    __syncthreads();
    int b = blockIdx.x;
    int pBeg = bucketStart[b], pEnd = bucketStart[b + 1];
    int g = t >> 4, q = t & 15;       // 32 groups of 16 lanes
    const uint2* x2 = (const uint2*)xh;
    for (int i = pBeg + g; i < pEnd; i += 64) {      // 2 streams per group
        unsigned p0 = pairs[i];
        int i1 = i + 32;
        bool has1 = i1 < pEnd;
        unsigned p1 = has1 ? pairs[i1] : 0;
        int s0 = (int)(p0 & ((1u << SRCB) - 1));
        uint2 u0 = x2[(size_t)s0 * 16 + q];
        uint2 u1 = has1 ? x2[(size_t)(p1 & ((1u << SRCB) - 1)) * 16 + q]
                        : make_uint2(0, 0);
        {
            int dloc = (int)(p0 >> SRCB);
            __half2 h0 = *reinterpret_cast<__half2*>(&u0.x);
            __half2 h1 = *reinterpret_cast<__half2*>(&u0.y);
            float* dp = &accL[dloc * F + q * 4];
            atomicAdd(dp + 0, __low2float(h0));
            atomicAdd(dp + 1, __high2float(h0));
            atomicAdd(dp + 2, __low2float(h1));
            atomicAdd(dp + 3, __high2float(h1));
            if (q == 0) atomicAdd(&cntL[dloc], 1);
        }
        if (has1) {
            int dloc = (int)(p1 >> SRCB);
            __half2 h0 = *reinterpret_cast<__half2*>(&u1.x);
            __half2 h1 = *reinterpret_cast<__half2*>(&u1.y);
            float* dp = &accL[dloc * F + q * 4];
            atomicAdd(dp + 0, __low2float(h0));
            atomicAdd(dp + 1, __high2float(h0));
            atomicAdd(dp + 2, __low2float(h1));
            atomicAdd(dp + 3, __high2float(h1));
            if (q == 0) atomicAdd(&cntL[dloc], 1);
        }
    }
    __syncthreads();
    int nodeBase = b << BSH;
    for (int idx = t; idx < NPB * 16; idx += 512) {
        int nl = idx >> 4, c4 = idx & 15;
        int node = nodeBase + nl;
        if (node >= nNodes) continue;
        float inv = 1.0f / fmaxf((float)cntL[nl], 1.0f);
        float4 v = *(float4*)&accL[nl * F + c4 * 4];
        v.x *= inv; v.y *= inv; v.z *= inv; v.w *= inv;
        ((float4*)agg)[(size_t)node * 16 + c4] = v;   // full-line coalesced
        if (c4 == 0) invdeg[node] = inv;
    }
}

// ---- dense12_reg: t2 = relu(agg@W1+b1)@W2, weights in registers (proven)
__global__ void dense12_reg(const float* __restrict__ agg,
                            const float* __restrict__ W1,
                            const float* __restrict__ b1,
                            const float* __restrict__ W2,
                            __half* __restrict__ t2, int nNodes) {
    __shared__ float xs[4][F];
    __shared__ float hs[4][F];
    __shared__ float red[4][4][17];
    int wave = threadIdx.x >> 6, lane = threadIdx.x & 63;
    int kk = lane >> 4, c = lane & 15;

    float w1[F];
#pragma unroll
    for (int k = 0; k < F; ++k) w1[k] = W1[k * F + lane];
    float b1l = b1[lane];
    float w2[16];
#pragma unroll
    for (int j = 0; j < 16; ++j) w2[j] = W2[(kk * 16 + j) * C + c];

    int step = gridDim.x * 4;
    int start = blockIdx.x * 4 + wave;
    int iters = (nNodes + step - 1) / step;
    for (int i = 0; i < iters; ++i) {
        int node = start + i * step;
        bool live = node < nNodes;
        xs[wave][lane] = live ? agg[(size_t)node * F + lane] : 0.0f;
        __syncthreads();
        float hacc = b1l;
#pragma unroll
        for (int k = 0; k < F; ++k) hacc = fmaf(xs[wave][k], w1[k], hacc);
        hs[wave][lane] = fmaxf(hacc, 0.0f);
        __syncthreads();
        float p = 0.0f;
#pragma unroll
        for (int j = 0; j < 16; ++j) p = fmaf(hs[wave][kk * 16 + j], w2[j], p);
        red[wave][kk][c] = p;
        __syncthreads();
        if (lane < C && live) {
            float o = red[wave][0][lane] + red[wave][1][lane]
                    + red[wave][2][lane] + red[wave][3][lane];
            t2[(size_t)node * C + lane] = __float2half_rn(o);
        }
        __syncthreads();
    }
}

// ---- out_bucket: layer-2 aggregation into LDS; 4-lane group per edge
__global__ void out_bucket(const __half* __restrict__ t2,
                           const unsigned* __restrict__ pairs,
                           const int* __restrict__ bucketStart,
                           const float* __restrict__ invdeg,
                           const float* __restrict__ b2,
                           float* __restrict__ out, int nNodes) {
    __shared__ float acc2[NPB * C];   // 8 KB
    int t = threadIdx.x;              // 512
    for (int i = t; i < NPB * C; i += 512) acc2[i] = 0.0f;
    __syncthreads();
    int b = blockIdx.x;
    int pBeg = bucketStart[b], pEnd = bucketStart[b + 1];
    int g = t >> 2, q = t & 3;        // 128 groups of 4 lanes
    const uint2* t2v = (const uint2*)t2;
    for (int i = pBeg + g; i < pEnd; i += 256) {     // 2 streams per group
        unsigned p0 = pairs[i];
        int i1 = i + 128;
        bool has1 = i1 < pEnd;
        unsigned p1 = has1 ? pairs[i1] : 0;
        uint2 u0 = t2v[(size_t)(p0 & ((1u << SRCB) - 1)) * 4 + q];
        uint2 u1 = has1 ? t2v[(size_t)(p1 & ((1u << SRCB) - 1)) * 4 + q]
                        : make_uint2(0, 0);
        {
            int dloc = (int)(p0 >> SRCB);
            __half2 h0 = *reinterpret_cast<__half2*>(&u0.x);
            __half2 h1 = *reinterpret_cast<__half2*>(&u0.y);
            float* dp = &acc2[dloc * C + q * 4];
            atomicAdd(dp + 0, __low2float(h0));
            atomicAdd(dp + 1, __high2float(h0));
            atomicAdd(dp + 2, __low2float(h1));
            atomicAdd(dp + 3, __high2float(h1));
        }
        if (has1) {
            int dloc = (int)(p1 >> SRCB);
            __half2 h0 = *reinterpret_cast<__half2*>(&u1.x);
            __half2 h1 = *reinterpret_cast<__half2*>(&u1.y);
            float* dp = &acc2[dloc * C + q * 4];
            atomicAdd(dp + 0, __low2float(h0));
            atomicAdd(dp + 1, __high2float(h0));
            atomicAdd(dp + 2, __low2float(h1));
            atomicAdd(dp + 3, __high2float(h1));
        }
    }
    __syncthreads();
    int nodeBase = b << BSH;
    for (int idx = t; idx < NPB * 4; idx += 512) {
        int nl = idx >> 2, c4 = idx & 3;
        int node = nodeBase + nl;
        if (node >= nNodes) continue;
        float inv = invdeg[node];
        float4 bv = ((const float4*)b2)[c4];
        float4 v = *(float4*)&acc2[nl * C + c4 * 4];
        float4 o;
        o.x = v.x * inv + bv.x;
        o.y = v.y * inv + bv.y;
        o.z = v.z * inv + bv.z;
        o.w = v.w * inv + bv.w;
        ((float4*)out)[(size_t)node * 4 + c4] = o;
    }
}

// ---------------------------------------------------------------- launch
extern "C" void kernel_launch(void* const* d_in, const int* in_sizes, int n_in,
                              void* d_out, int out_size, void* d_ws, size_t ws_size,
                              hipStream_t stream) {
    const float* features = (const float*)d_in[0];
    const int*   src      = (const int*)d_in[1];
    const int*   dst      = (const int*)d_in[2];
    const float* W1       = (const float*)d_in[3];
    const float* b1       = (const float*)d_in[4];
    const float* W2       = (const float*)d_in[5];
    const float* b2       = (const float*)d_in[6];
    float*       out      = (float*)d_out;

    const int nNodes = in_sizes[0] / F;           // 100000
    const int nEdges = in_sizes[1];               // 1600000
    const int NBLK  = (nEdges + EPB - 1) / EPB;   // 782

    // ---- workspace carve-up (peak ~50.9 MiB; round-1 proved >=51.6 MiB works)
    char* ws = (char*)d_ws;
    auto align = [](size_t x) { return (x + 255) / 256 * 256; };
    int* bucketCount  = (int*)ws;    ws += align((size_t)NBK * 4);
    int* bucketStart  = (int*)ws;    ws += align((size_t)(NBK + 1) * 4);
    int* blockHist    = (int*)ws;    ws += align((size_t)NBLK * NBK * 4);
    unsigned* pairs   = (unsigned*)ws; ws += align((size_t)nEdges * 4);
    float* invdeg     = (float*)ws;  ws += align((size_t)nNodes * 4);
    __half* xh        = (__half*)ws; ws += align((size_t)nNodes * F * 2);
    float* agg        = (float*)ws;  ws += align((size_t)nNodes * F * 4);
    __half* t2h       = (__half*)ws; ws += align((size_t)nNodes * C * 2);

    hipMemsetAsync(bucketCount, 0, (size_t)NBK * sizeof(int), stream);

    // ---- bucketed edge layout (no per-node CSR needed)
    prep<<<NBLK, 256, 0, stream>>>(features, xh, nNodes * F / 4,
                                   dst, bucketCount, blockHist, nEdges);
    bucket_scan<<<1, 1024, 0, stream>>>(bucketCount, bucketStart);
    partition<<<NBLK, 256, 0, stream>>>(src, dst, blockHist, bucketStart, pairs, nEdges);

    // ---- layer 1: bucket-LDS aggregation, then register-resident dense
    agg_bucket<<<NBK, 512, 0, stream>>>(xh, pairs, bucketStart, agg, invdeg, nNodes);
    dense12_reg<<<2048, 256, 0, stream>>>(agg, W1, b1, W2, t2h, nNodes);

    // ---- layer 2: bucket-LDS aggregation of t2
    out_bucket<<<NBK, 512, 0, stream>>>(t2h, pairs, bucketStart, invdeg, b2, out, nNodes);
}

// Round 15
// 151.723 us; speedup vs baseline: 6.1839x; 6.1839x over previous
//
#include <hip/hip_runtime.h>
#include <hip/hip_fp16.h>

static constexpr int F = 64;      // IN_FEATS == HIDDEN
static constexpr int C = 16;      // NUM_CLASSES
static constexpr int EPB = 2048;  // edges per block (hist/partition)
static constexpr int BSH = 9;     // bucket shift: 512 nodes/bucket
static constexpr int SRCB = 17;   // src id bits (nNodes <= 131072)
static constexpr int NPG = 4;     // nodes per 16-lane group (gathers)

// -------- prep: fp32->fp16 convert + per-block histogram + SLICE RESERVATION
// blockHist[b*256+t] holds this block's RELATIVE base within bucket t.
__global__ void prep(const float* __restrict__ x, __half* __restrict__ xh, int n4,
                     const int* __restrict__ dst, int* __restrict__ bucketCount,
                     int* __restrict__ blockHist, int nEdges) {
    int stride = gridDim.x * blockDim.x;
    for (int i = blockIdx.x * blockDim.x + threadIdx.x; i < n4; i += stride) {
        float4 v = ((const float4*)x)[i];
        __half2 p0 = __floats2half2_rn(v.x, v.y);
        __half2 p1 = __floats2half2_rn(v.z, v.w);
        uint2 o;
        o.x = *reinterpret_cast<unsigned*>(&p0);
        o.y = *reinterpret_cast<unsigned*>(&p1);
        ((uint2*)xh)[i] = o;
    }
    __shared__ int h[256];
    int t = threadIdx.x;
    h[t] = 0;
    __syncthreads();
    int e0 = blockIdx.x * EPB;
    for (int i = 0; i < EPB / 256; ++i) {
        int e = e0 + i * 256 + t;
        if (e < nEdges) atomicAdd(&h[dst[e] >> BSH], 1);
    }
    __syncthreads();
    // reserve this block's contiguous slice in bucket t (relative offset)
    blockHist[blockIdx.x * 256 + t] = h[t] ? atomicAdd(&bucketCount[t], h[t]) : 0;
}

// ------------------------------- exclusive scan of 256 bucket counts (1 block)
__global__ void bucket_scan(const int* __restrict__ bucketCount,
                            int* __restrict__ bucketStart) {
    __shared__ int s[256];
    int t = threadIdx.x;
    s[t] = bucketCount[t];
    __syncthreads();
    for (int o = 1; o < 256; o <<= 1) {
        int v = (t >= o) ? s[t - o] : 0;
        __syncthreads();
        s[t] += v;
        __syncthreads();
    }
    bucketStart[t] = (t > 0) ? s[t - 1] : 0;
    if (t == 255) bucketStart[256] = s[255];
}

// ------------- partition: place edges into pre-reserved bucket slices
__global__ void partition(const int* __restrict__ src, const int* __restrict__ dst,
                          const int* __restrict__ blockHist,
                          const int* __restrict__ bucketStart,
                          unsigned* __restrict__ pairs, int nEdges) {
    __shared__ int base[256];
    __shared__ int rank[256];
    int t = threadIdx.x;
    rank[t] = 0;
    base[t] = bucketStart[t] + blockHist[blockIdx.x * 256 + t];
    __syncthreads();
    int e0 = blockIdx.x * EPB;
    for (int i = 0; i < EPB / 256; ++i) {
        int e = e0 + i * 256 + t;
        if (e < nEdges) {
            int d = dst[e];
            int b = d >> BSH;
            int r = atomicAdd(&rank[b], 1);
            pairs[base[b] + r] =
                ((unsigned)(d & ((1 << BSH) - 1)) << SRCB) | (unsigned)src[e];
        }
    }
}

// ------- per-bucket: degrees -> local scan -> rowstart + csr (single writer)
__global__ void bucket_csr(const unsigned* __restrict__ pairs,
                           const int* __restrict__ bucketStart,
                           int* __restrict__ rowstart, int* __restrict__ csr,
                           int nNodes, int nEdges) {
    __shared__ int cnt[512];
    __shared__ int s[512];
    __shared__ int cur[512];
    int t = threadIdx.x;
    int b = blockIdx.x;
    int nodeBase = b << BSH;
    int pBeg = bucketStart[b], pEnd = bucketStart[b + 1];
    cnt[t] = 0;
    __syncthreads();
    for (int i = pBeg + t; i < pEnd; i += 512)
        atomicAdd(&cnt[pairs[i] >> SRCB], 1);
    __syncthreads();
    s[t] = cnt[t];
    __syncthreads();
    for (int o = 1; o < 512; o <<= 1) {
        int v = (t >= o) ? s[t - o] : 0;
        __syncthreads();
        s[t] += v;
        __syncthreads();
    }
    int rs = pBeg + ((t > 0) ? s[t - 1] : 0);
    int node = nodeBase + t;
    if (node < nNodes) rowstart[node] = rs;
    cur[t] = rs;
    __syncthreads();
    for (int i = pBeg + t; i < pEnd; i += 512) {
        unsigned p = pairs[i];
        int pos = atomicAdd(&cur[p >> SRCB], 1);
        csr[pos] = (int)(p & ((1u << SRCB) - 1));
    }
    if (b == 0 && t == 0) rowstart[nNodes] = nEdges;
}

// ---- gather_h2: 16-lane group owns NPG consecutive nodes (round 11, proven)
__global__ void gather_h2(const __half* __restrict__ xh,
                          const int* __restrict__ rowstart,
                          const int* __restrict__ csr,
                          float* __restrict__ agg, int nNodes) {
    int gid = (blockIdx.x * blockDim.x + threadIdx.x) >> 4;
    int q = threadIdx.x & 15;
    int nodeBase = gid * NPG;
    if (nodeBase >= nNodes) return;
    const uint2* x2 = (const uint2*)xh;
    int rs[NPG + 1];
#pragma unroll
    for (int i = 0; i <= NPG; ++i) rs[i] = rowstart[min(nodeBase + i, nNodes)];
#pragma unroll
    for (int i = 0; i < NPG; ++i) {
        int node = nodeBase + i;
        if (node >= nNodes) break;
        int beg = rs[i], end = rs[i + 1];
        float4 a0 = make_float4(0.f, 0.f, 0.f, 0.f);
        float4 a1 = make_float4(0.f, 0.f, 0.f, 0.f);
        float4 a2 = make_float4(0.f, 0.f, 0.f, 0.f);
        float4 a3 = make_float4(0.f, 0.f, 0.f, 0.f);
        int k = beg;
        for (; k + 4 <= end; k += 4) {   // 4 independent row chains
            int s0 = csr[k], s1 = csr[k + 1], s2 = csr[k + 2], s3 = csr[k + 3];
            uint2 u0 = x2[(size_t)s0 * 16 + q];
            uint2 u1 = x2[(size_t)s1 * 16 + q];
            uint2 u2 = x2[(size_t)s2 * 16 + q];
            uint2 u3 = x2[(size_t)s3 * 16 + q];
            __half2 h00 = *reinterpret_cast<__half2*>(&u0.x);
            __half2 h01 = *reinterpret_cast<__half2*>(&u0.y);
            a0.x += __low2float(h00); a0.y += __high2float(h00);
            a0.z += __low2float(h01); a0.w += __high2float(h01);
            __half2 h10 = *reinterpret_cast<__half2*>(&u1.x);
            __half2 h11 = *reinterpret_cast<__half2*>(&u1.y);
            a1.x += __low2float(h10); a1.y += __high2float(h10);
            a1.z += __low2float(h11); a1.w += __high2float(h11);
            __half2 h20 = *reinterpret_cast<__half2*>(&u2.x);
            __half2 h21 = *reinterpret_cast<__half2*>(&u2.y);
            a2.x += __low2float(h20); a2.y += __high2float(h20);
            a2.z += __low2float(h21); a2.w += __high2float(h21);
            __half2 h30 = *reinterpret_cast<__half2*>(&u3.x);
            __half2 h31 = *reinterpret_cast<__half2*>(&u3.y);
            a3.x += __low2float(h30); a3.y += __high2float(h30);
            a3.z += __low2float(h31); a3.w += __high2float(h31);
        }
        for (; k < end; ++k) {           // tail
            int s0 = csr[k];
            uint2 u0 = x2[(size_t)s0 * 16 + q];
            __half2 h00 = *reinterpret_cast<__half2*>(&u0.x);
            __half2 h01 = *reinterpret_cast<__half2*>(&u0.y);
            a0.x += __low2float(h00); a0.y += __high2float(h00);
            a0.z += __low2float(h01); a0.w += __high2float(h01);
        }
        float inv = 1.0f / fmaxf((float)(end - beg), 1.0f);
        float4 o;
        o.x = ((a0.x + a1.x) + (a2.x + a3.x)) * inv;
        o.y = ((a0.y + a1.y) + (a2.y + a3.y)) * inv;
        o.z = ((a0.z + a1.z) + (a2.z + a3.z)) * inv;
        o.w = ((a0.w + a1.w) + (a2.w + a3.w)) * inv;
        ((float4*)agg)[(size_t)node * 16 + q] = o;   // 256B coalesced per node
    }
}

// ---- dense12_reg: t2 = relu(agg@W1+b1)@W2, weights in registers (round 10)
__global__ void dense12_reg(const float* __restrict__ agg,
                            const float* __restrict__ W1,
                            const float* __restrict__ b1,
                            const float* __restrict__ W2,
                            __half* __restrict__ t2, int nNodes) {
    __shared__ float xs[4][F];
    __shared__ float hs[4][F];
    __shared__ float red[4][4][17];
    int wave = threadIdx.x >> 6, lane = threadIdx.x & 63;
    int kk = lane >> 4, c = lane & 15;

    float w1[F];
#pragma unroll
    for (int k = 0; k < F; ++k) w1[k] = W1[k * F + lane];
    float b1l = b1[lane];
    float w2[16];
#pragma unroll
    for (int j = 0; j < 16; ++j) w2[j] = W2[(kk * 16 + j) * C + c];

    int step = gridDim.x * 4;
    int start = blockIdx.x * 4 + wave;
    int iters = (nNodes + step - 1) / step;
    for (int i = 0; i < iters; ++i) {
        int node = start + i * step;
        bool live = node < nNodes;
        xs[wave][lane] = live ? agg[(size_t)node * F + lane] : 0.0f;
        __syncthreads();
        float hacc = b1l;
#pragma unroll
        for (int k = 0; k < F; ++k) hacc = fmaf(xs[wave][k], w1[k], hacc);
        hs[wave][lane] = fmaxf(hacc, 0.0f);
        __syncthreads();
        float p = 0.0f;
#pragma unroll
        for (int j = 0; j < 16; ++j) p = fmaf(hs[wave][kk * 16 + j], w2[j], p);
        red[wave][kk][c] = p;
        __syncthreads();
        if (lane < C && live) {
            float o = red[wave][0][lane] + red[wave][1][lane]
                    + red[wave][2][lane] + red[wave][3][lane];
            t2[(size_t)node * C + lane] = __float2half_rn(o);
        }
        __syncthreads();
    }
}

// ---- gather16c: layer-2 aggregation (round 11, proven)
__global__ void gather16c(const __half* __restrict__ t2,
                          const int* __restrict__ rowstart,
                          const int* __restrict__ csr,
                          const float* __restrict__ b2,
                          float* __restrict__ out, int nNodes) {
    int gid = (blockIdx.x * blockDim.x + threadIdx.x) >> 4;
    int c = threadIdx.x & 15;
    int nodeBase = gid * NPG;
    if (nodeBase >= nNodes) return;
    float b2c = b2[c];
    int rs[NPG + 1];
#pragma unroll
    for (int i = 0; i <= NPG; ++i) rs[i] = rowstart[min(nodeBase + i, nNodes)];
#pragma unroll
    for (int i = 0; i < NPG; ++i) {
        int node = nodeBase + i;
        if (node >= nNodes) break;
        int beg = rs[i], end = rs[i + 1];
        float a0 = 0.f, a1 = 0.f, a2 = 0.f, a3 = 0.f;
        int k = beg;
        for (; k + 4 <= end; k += 4) {
            int s0 = csr[k], s1 = csr[k + 1], s2 = csr[k + 2], s3 = csr[k + 3];
            a0 += __half2float(t2[(size_t)s0 * C + c]);
            a1 += __half2float(t2[(size_t)s1 * C + c]);
            a2 += __half2float(t2[(size_t)s2 * C + c]);
            a3 += __half2float(t2[(size_t)s3 * C + c]);
        }
        for (; k < end; ++k) a0 += __half2float(t2[(size_t)csr[k] * C + c]);
        float d = fmaxf((float)(end - beg), 1.0f);
        out[(size_t)node * C + c] = ((a0 + a1) + (a2 + a3)) / d + b2c;
    }
}

// ---------------------------------------------------------------- launch
extern "C" void kernel_launch(void* const* d_in, const int* in_sizes, int n_in,
                              void* d_out, int out_size, void* d_ws, size_t ws_size,
                              hipStream_t stream) {
    const float* features = (const float*)d_in[0];
    const int*   src      = (const int*)d_in[1];
    const int*   dst      = (const int*)d_in[2];
    const float* W1       = (const float*)d_in[3];
    const float* b1       = (const float*)d_in[4];
    const float* W2       = (const float*)d_in[5];
    const float* b2       = (const float*)d_in[6];
    float*       out      = (float*)d_out;

    const int nNodes = in_sizes[0] / F;           // 100000
    const int nEdges = in_sizes[1];               // 1600000
    const int NBUCK = (nNodes + 511) >> BSH;      // 196 (<= 256)
    const int NBLK  = (nEdges + EPB - 1) / EPB;   // 782

    // ---- workspace carve-up (peak ~49.7 MiB; round-1 proved >=51.6 MiB works)
    char* ws = (char*)d_ws;
    auto align = [](size_t x) { return (x + 255) / 256 * 256; };
    int* bucketCount  = (int*)ws;    ws += align(256 * 4);
    int* bucketStart  = (int*)ws;    ws += align(257 * 4);
    int* blockHist    = (int*)ws;    ws += align((size_t)NBLK * 256 * 4);
    int* rowstart     = (int*)ws;    ws += align((size_t)(nNodes + 1) * 4);
    int* csr          = (int*)ws;    ws += align((size_t)nEdges * 4);
    __half* xh        = (__half*)ws; ws += align((size_t)nNodes * F * 2);
    float* agg        = (float*)ws;  ws += align((size_t)nNodes * F * 4);
    __half* t2h       = (__half*)ws; ws += align((size_t)nNodes * C * 2);
    unsigned* pairs   = (unsigned*)agg;  // 6.4 MB inside agg; dead before gather

    hipMemsetAsync(bucketCount, 0, 256 * sizeof(int), stream);

    // ---- prep (convert + hist + slice reservation) then CSR build
    prep<<<NBLK, 256, 0, stream>>>(features, xh, nNodes * F / 4,
                                   dst, bucketCount, blockHist, nEdges);
    bucket_scan<<<1, 256, 0, stream>>>(bucketCount, bucketStart);
    partition<<<NBLK, 256, 0, stream>>>(src, dst, blockHist, bucketStart, pairs, nEdges);
    bucket_csr<<<NBUCK, 512, 0, stream>>>(pairs, bucketStart, rowstart, csr,
                                          nNodes, nEdges);

    // ---- layer 1 gather (long-lived groups) + register-resident dense
    {
        int nGroups = (nNodes + NPG - 1) / NPG;            // 25000
        int blocks = (nGroups * 16 + 255) / 256;           // 1563
        gather_h2<<<blocks, 256, 0, stream>>>(xh, rowstart, csr, agg, nNodes);
    }
    dense12_reg<<<2048, 256, 0, stream>>>(agg, W1, b1, W2, t2h, nNodes);

    // ---- layer 2 aggregation (long-lived groups)
    {
        int nGroups = (nNodes + NPG - 1) / NPG;
        int blocks = (nGroups * 16 + 255) / 256;
        gather16c<<<blocks, 256, 0, stream>>>(t2h, rowstart, csr, b2, out, nNodes);
    }
}